// Round 4
// baseline (689.192 us; speedup 1.0000x reference)
//
#include <hip/hip_runtime.h>

#define BN_EPS 1e-5f

typedef __attribute__((ext_vector_type(8))) short bf16x8;
typedef __attribute__((ext_vector_type(4))) float f32x4;

__device__ __forceinline__ short f2bf(float f) {
    union { float f; unsigned u; } v; v.f = f;
    unsigned r = (v.u + 0x7fffu + ((v.u >> 16) & 1u)) >> 16;
    return (short)r;
}
__device__ __forceinline__ float bflo(unsigned d) {
    union { unsigned u; float f; } v; v.u = d << 16; return v.f;
}
__device__ __forceinline__ float bfhi(unsigned d) {
    union { unsigned u; float f; } v; v.u = d & 0xffff0000u; return v.f;
}

// ---------------------------------------------------------------------------
// Build CSR offsets from sorted dst. off[n] = first edge index with dst >= n.
// ---------------------------------------------------------------------------
__global__ __launch_bounds__(256) void build_off_k(const int* __restrict__ dst,
                                                   int* __restrict__ off, int E, int N) {
    int i = blockIdx.x * 256 + threadIdx.x;
    if (i > E) return;
    int cur  = (i < E) ? dst[i] : N;
    int prev = (i == 0) ? -1 : dst[i - 1];
    for (int n = prev + 1; n <= cur; ++n) off[n] = i;
}

__global__ void zero_k(float* p, int n) {
    int i = blockIdx.x * blockDim.x + threadIdx.x;
    if (i < n) p[i] = 0.f;
}

// Transpose + convert weights: Wt[c][k] = bf16(W[k][c]).
__global__ __launch_bounds__(256) void wtrans_k(const float* __restrict__ W,
                                                short* __restrict__ Wt, int K, int C) {
    int i = blockIdx.x * 256 + threadIdx.x;
    if (i >= K * C) return;
    int c = i / K, k = i % K;
    Wt[i] = f2bf(W[k * C + c]);
}

// ---------------------------------------------------------------------------
// MFMA GEMM: Mp (bf16, PLANE-major) = X[N x 128] (fp32, cvt->bf16 in-reg) @ W
// Plane g (16 output channels, g = n-frag index) is a contiguous N x 16 bf16
// region at Mp + g*N*16 -> 3.2 MB per plane, fits a per-XCD L2 for the gather.
// W pre-transposed bf16: Wt[OUTC][128]. Block = 256 thr (4 waves), 128 rows.
// ---------------------------------------------------------------------------
template <int OUTC>
__global__ __launch_bounds__(256) void mgemm_k(const float* __restrict__ X,
                                               const short* __restrict__ Wt,
                                               short* __restrict__ Mp, int N) {
    constexpr int NR = OUTC / 16;
    __shared__ short sW[OUTC][136];          // 272B stride: 2-way conflict = free

    const int tid = threadIdx.x;
    for (int q = tid; q < OUTC * 16; q += 256) {
        int r = q >> 4, s = q & 15;
        *(int4*)&sW[r][s * 8] = ((const int4*)Wt)[q];
    }
    __syncthreads();

    const int wave = tid >> 6, lane = tid & 63;
    const int lr = lane & 15, lg = lane >> 4;
    const int row0 = blockIdx.x * 128 + wave * 32;
    const size_t planeStride = (size_t)N * 16;

    f32x4 acc[2][NR];
    #pragma unroll
    for (int m = 0; m < 2; ++m)
        #pragma unroll
        for (int n = 0; n < NR; ++n) acc[m][n] = (f32x4){0.f, 0.f, 0.f, 0.f};

    #pragma unroll
    for (int kk = 0; kk < 4; ++kk) {
        bf16x8 a[2];
        #pragma unroll
        for (int m = 0; m < 2; ++m) {
            int row = row0 + m * 16 + lr;
            float4 x0 = make_float4(0.f, 0.f, 0.f, 0.f), x1 = x0;
            if (row < N) {
                const float4* p = (const float4*)&X[(size_t)row * 128 + kk * 32 + lg * 8];
                x0 = p[0]; x1 = p[1];
            }
            a[m][0] = f2bf(x0.x); a[m][1] = f2bf(x0.y);
            a[m][2] = f2bf(x0.z); a[m][3] = f2bf(x0.w);
            a[m][4] = f2bf(x1.x); a[m][5] = f2bf(x1.y);
            a[m][6] = f2bf(x1.z); a[m][7] = f2bf(x1.w);
        }
        #pragma unroll
        for (int n = 0; n < NR; ++n) {
            bf16x8 b = *(const bf16x8*)&sW[n * 16 + lr][kk * 32 + lg * 8];
            acc[0][n] = __builtin_amdgcn_mfma_f32_16x16x32_bf16(a[0], b, acc[0][n], 0, 0, 0);
            acc[1][n] = __builtin_amdgcn_mfma_f32_16x16x32_bf16(a[1], b, acc[1][n], 0, 0, 0);
        }
    }

    #pragma unroll
    for (int m = 0; m < 2; ++m)
        #pragma unroll
        for (int r = 0; r < 4; ++r) {
            int row = row0 + m * 16 + lg * 4 + r;
            if (row < N) {
                #pragma unroll
                for (int n = 0; n < NR; ++n)
                    Mp[(size_t)n * planeStride + row * 16 + lr] = f2bf(acc[m][n][r]);
            }
        }
}

// ---------------------------------------------------------------------------
// Plane-partitioned segment-sum gather (dst sorted -> CSR, no atomics).
// plane = blockIdx % NP  -> XCD-affine under round-robin blockIdx%8 mapping,
// so each XCD's L2 caches one 3.2 MB plane -> gathers are L2 hits.
// Wave handles 2 nodes; per node: 8 edges x 8 dword-lanes (16 ch), shfl
// broadcast of src, butterfly-reduce edge dim (xor 8/16/32), lanes 0-7 write.
// ---------------------------------------------------------------------------
template <int C>
__global__ __launch_bounds__(256) void pagg_k(const short* __restrict__ Mp,
                                              const int* __restrict__ src,
                                              const int* __restrict__ off,
                                              const float* __restrict__ bias,
                                              float* __restrict__ H, int N) {
    constexpr int NP = C / 16;               // planes (8 or 4)
    const int plane = blockIdx.x % NP;
    const int nb    = blockIdx.x / NP;
    const unsigned* __restrict__ P =
        (const unsigned*)Mp + (size_t)plane * N * 8;   // 8 dwords per node-slice

    const int wave = threadIdx.x >> 6, lane = threadIdx.x & 63;
    const int e8 = lane >> 3, c = lane & 7;

    #pragma unroll
    for (int w = 0; w < 2; ++w) {
        const int node = nb * 8 + wave * 2 + w;
        if (node >= N) continue;
        const int e0 = off[node], e1 = off[node + 1];

        float2 acc = make_float2(0.f, 0.f);
        for (int base = e0; base < e1; base += 64) {
            int e = base + lane;
            int s = (e < e1) ? src[e] : 0;
            int cnt = min(64, e1 - base);
            int ngrp = (cnt + 7) >> 3;
            #pragma unroll 4
            for (int j = 0; j < ngrp; ++j) {
                int idx = (j << 3) + e8;
                int si = __shfl(s, idx);
                unsigned d = (idx < cnt) ? P[(size_t)si * 8 + c] : 0u;
                acc.x += bflo(d);
                acc.y += bfhi(d);
            }
        }
        // reduce over edge-slot dimension (lane bits 3..5)
        #pragma unroll
        for (int dlt = 8; dlt < 64; dlt <<= 1) {
            acc.x += __shfl_xor(acc.x, dlt);
            acc.y += __shfl_xor(acc.y, dlt);
        }
        if (e8 == 0) {
            float2 bv = *(const float2*)&bias[plane * 16 + c * 2];
            *(float2*)&H[(size_t)node * C + plane * 16 + c * 2] =
                make_float2(acc.x + bv.x, acc.y + bv.y);
        }
    }
}

// ---------------------------------------------------------------------------
// BN column stats (sum, sumsq) with per-block partials + atomics.
// ---------------------------------------------------------------------------
__global__ __launch_bounds__(256) void stats_k(const float* __restrict__ H,
                                               float* __restrict__ stats, int N) {
    const int c = threadIdx.x & 127;
    const int half = threadIdx.x >> 7;
    float sum = 0.f, sq = 0.f;
    for (int r = blockIdx.x * 2 + half; r < N; r += gridDim.x * 2) {
        float v = H[r * 128 + c];
        sum += v; sq = fmaf(v, v, sq);
    }
    __shared__ float sS[128], sQ[128];
    if (half) { sS[c] = sum; sQ[c] = sq; }
    __syncthreads();
    if (!half) {
        atomicAdd(&stats[c], sum + sS[c]);
        atomicAdd(&stats[128 + c], sq + sQ[c]);
    }
}

__global__ void bnfin_k(const float* __restrict__ stats, const float* __restrict__ gamma,
                        const float* __restrict__ beta, float* __restrict__ ss, float invN) {
    int c = threadIdx.x;   // 128 threads
    float mu  = stats[c] * invN;
    float var = fmaf(-mu, mu, stats[128 + c] * invN);
    float sc  = gamma[c] * rsqrtf(var + BN_EPS);
    ss[c]       = sc;
    ss[128 + c] = fmaf(-mu, sc, beta[c]);
}

// Fused BN-apply + residual + ReLU, elementwise float4, safe in-place.
__global__ __launch_bounds__(256) void apply_k(const float* H,
                                               const float* __restrict__ R,
                                               const float* __restrict__ ss,
                                               float* Xn, int n4) {
    int i = blockIdx.x * 256 + threadIdx.x;
    if (i >= n4) return;
    int c4 = (i & 31) << 2;
    float4 h = ((const float4*)H)[i];
    float4 r = ((const float4*)R)[i];
    float4 o;
    o.x = fmaxf(fmaf(h.x, ss[c4 + 0], ss[128 + c4 + 0]) + r.x, 0.f);
    o.y = fmaxf(fmaf(h.y, ss[c4 + 1], ss[128 + c4 + 1]) + r.y, 0.f);
    o.z = fmaxf(fmaf(h.z, ss[c4 + 2], ss[128 + c4 + 2]) + r.z, 0.f);
    o.w = fmaxf(fmaf(h.w, ss[c4 + 3], ss[128 + c4 + 3]) + r.w, 0.f);
    ((float4*)Xn)[i] = o;
}

// ---------------------------------------------------------------------------
extern "C" void kernel_launch(void* const* d_in, const int* in_sizes, int n_in,
                              void* d_out, int out_size, void* d_ws, size_t ws_size,
                              hipStream_t stream) {
    const float* x   = (const float*)d_in[0];
    const int*   src = (const int*)d_in[1];
    const int*   dst = (const int*)d_in[2];
    const float* W0  = (const float*)d_in[3];
    const float* b0  = (const float*)d_in[4];
    const float* W1  = (const float*)d_in[5];
    const float* b1  = (const float*)d_in[6];
    const float* W2  = (const float*)d_in[7];
    const float* b2  = (const float*)d_in[8];
    const float* g0  = (const float*)d_in[9];
    const float* be0 = (const float*)d_in[10];
    const float* g1  = (const float*)d_in[11];
    const float* be1 = (const float*)d_in[12];
    float* out = (float*)d_out;

    const int N = in_sizes[0] / 128;
    const int E = in_sizes[1];

    // workspace: bf16 plane-major M + 2 fp32 N x 128 buffers + Wt + offsets
    char*  ws   = (char*)d_ws;
    size_t bufB = (size_t)N * 128 * sizeof(float);
    short* Mb = (short*)(ws);                 // N x 128 bf16, plane-major
    float* B  = (float*)(ws + bufB);
    float* Cb = (float*)(ws + 2 * bufB);
    size_t p  = 3 * bufB;
    int*   off = (int*)(ws + p);
    p += ((size_t)(N + 1) * sizeof(int) + 255) & ~(size_t)255;
    float* stats0 = (float*)(ws + p); p += 1024;
    float* stats1 = (float*)(ws + p); p += 1024;
    float* ss     = (float*)(ws + p); p += 1024;
    short* Wt0    = (short*)(ws + p); p += 128 * 128 * 2;
    short* Wt1    = (short*)(ws + p); p += 128 * 128 * 2;
    short* Wt2    = (short*)(ws + p); p += 128 * 64 * 2;

    const dim3 blk(256);
    const int gGemm   = (N + 127) / 128;
    const int gAgg128 = 8 * ((N + 7) / 8);
    const int gAgg64  = 4 * ((N + 7) / 8);
    const int gApply  = (N * 32 + 255) / 256;
    const float invN = 1.f / (float)N;

    zero_k<<<2, blk, 0, stream>>>(stats0, 512);
    wtrans_k<<<64, blk, 0, stream>>>(W0, Wt0, 128, 128);
    wtrans_k<<<64, blk, 0, stream>>>(W1, Wt1, 128, 128);
    wtrans_k<<<32, blk, 0, stream>>>(W2, Wt2, 128, 64);
    build_off_k<<<(E + 256) / 256, blk, 0, stream>>>(dst, off, E, N);

    // ---- layer 0 ----
    mgemm_k<128><<<gGemm, blk, 0, stream>>>(x, Wt0, Mb, N);
    pagg_k<128><<<gAgg128, blk, 0, stream>>>(Mb, src, off, b0, B, N);
    stats_k<<<1024, blk, 0, stream>>>(B, stats0, N);
    bnfin_k<<<1, 128, 0, stream>>>(stats0, g0, be0, ss, invN);
    apply_k<<<gApply, blk, 0, stream>>>(B, x, ss, B, N * 32);

    // ---- layer 1 ----
    mgemm_k<128><<<gGemm, blk, 0, stream>>>(B, Wt1, Mb, N);
    pagg_k<128><<<gAgg128, blk, 0, stream>>>(Mb, src, off, b1, Cb, N);
    stats_k<<<1024, blk, 0, stream>>>(Cb, stats1, N);
    bnfin_k<<<1, 128, 0, stream>>>(stats1, g1, be1, ss, invN);
    apply_k<<<gApply, blk, 0, stream>>>(Cb, B, ss, Cb, N * 32);

    // ---- final conv ----
    mgemm_k<64><<<gGemm, blk, 0, stream>>>(Cb, Wt2, Mb, N);
    pagg_k<64><<<gAgg64, blk, 0, stream>>>(Mb, src, off, b2, out, N);
}

// Round 5
// 322.504 us; speedup vs baseline: 2.1370x; 2.1370x over previous
//
#include <hip/hip_runtime.h>

#define BN_EPS 1e-5f

typedef __attribute__((ext_vector_type(8))) short bf16x8;
typedef __attribute__((ext_vector_type(4))) float f32x4;

__device__ __forceinline__ short f2bf(float f) {
    union { float f; unsigned u; } v; v.f = f;
    unsigned r = (v.u + 0x7fffu + ((v.u >> 16) & 1u)) >> 16;
    return (short)r;
}
__device__ __forceinline__ float bflo(unsigned d) {
    union { unsigned u; float f; } v; v.u = d << 16; return v.f;
}
__device__ __forceinline__ float bfhi(unsigned d) {
    union { unsigned u; float f; } v; v.u = d & 0xffff0000u; return v.f;
}

// ---------------------------------------------------------------------------
// Build CSR offsets from sorted dst. off[n] = first edge index with dst >= n.
// ---------------------------------------------------------------------------
__global__ __launch_bounds__(256) void build_off_k(const int* __restrict__ dst,
                                                   int* __restrict__ off, int E, int N) {
    int i = blockIdx.x * 256 + threadIdx.x;
    if (i > E) return;
    int cur  = (i < E) ? dst[i] : N;
    int prev = (i == 0) ? -1 : dst[i - 1];
    for (int n = prev + 1; n <= cur; ++n) off[n] = i;
}

__global__ void zero_k(float* p, int n) {
    int i = blockIdx.x * blockDim.x + threadIdx.x;
    if (i < n) p[i] = 0.f;
}

// Transpose + convert weights: Wt[c][k] = bf16(W[k][c]).
__global__ __launch_bounds__(256) void wtrans_k(const float* __restrict__ W,
                                                short* __restrict__ Wt, int K, int C) {
    int i = blockIdx.x * 256 + threadIdx.x;
    if (i >= K * C) return;
    int c = i / K, k = i % K;
    Wt[i] = f2bf(W[k * C + c]);
}

// ---------------------------------------------------------------------------
// MFMA GEMM, 3 modes of A-input fusion:
//   MODE 0: A = bf16(X fp32)                       (layer-0 input)
//   MODE 1: A = relu(H*sc+sh + R_fp32); also write A to X1 (bf16)  (layer 1)
//   MODE 2: A = relu(H*sc+sh + bf2f(R_bf16))                       (layer 2)
// Output M row-major bf16 [N][OUTC]. Block = 256 thr (4 waves), 128 rows.
// mfma_f32_16x16x32_bf16 layouts per m89/m92-verified mapping.
// ---------------------------------------------------------------------------
template <int OUTC, int MODE>
__global__ __launch_bounds__(256) void mgemm_k(const float* __restrict__ X,
                                               const short* __restrict__ Wt,
                                               short* __restrict__ M,
                                               const float* __restrict__ ss,
                                               const void* __restrict__ Rp,
                                               short* __restrict__ X1, int N) {
    constexpr int NR = OUTC / 16;
    __shared__ short sW[OUTC][136];          // 272B stride: 2-way conflict = free

    const int tid = threadIdx.x;
    for (int q = tid; q < OUTC * 16; q += 256) {
        int r = q >> 4, s = q & 15;
        *(int4*)&sW[r][s * 8] = ((const int4*)Wt)[q];
    }
    __syncthreads();

    const int wave = tid >> 6, lane = tid & 63;
    const int lr = lane & 15, lg = lane >> 4;
    const int row0 = blockIdx.x * 128 + wave * 32;

    f32x4 acc[2][NR];
    #pragma unroll
    for (int m = 0; m < 2; ++m)
        #pragma unroll
        for (int n = 0; n < NR; ++n) acc[m][n] = (f32x4){0.f, 0.f, 0.f, 0.f};

    #pragma unroll
    for (int kk = 0; kk < 4; ++kk) {
        bf16x8 a[2];
        const int ch0 = kk * 32 + lg * 8;
        #pragma unroll
        for (int m = 0; m < 2; ++m) {
            int row = row0 + m * 16 + lr;
            float v[8] = {0.f, 0.f, 0.f, 0.f, 0.f, 0.f, 0.f, 0.f};
            if (row < N) {
                const float4* p = (const float4*)&X[(size_t)row * 128 + ch0];
                float4 h0 = p[0], h1 = p[1];
                v[0] = h0.x; v[1] = h0.y; v[2] = h0.z; v[3] = h0.w;
                v[4] = h1.x; v[5] = h1.y; v[6] = h1.z; v[7] = h1.w;
                if constexpr (MODE != 0) {
                    float4 sc0 = *(const float4*)&ss[ch0];
                    float4 sc1 = *(const float4*)&ss[ch0 + 4];
                    float4 sh0 = *(const float4*)&ss[128 + ch0];
                    float4 sh1 = *(const float4*)&ss[128 + ch0 + 4];
                    float sc[8] = {sc0.x, sc0.y, sc0.z, sc0.w, sc1.x, sc1.y, sc1.z, sc1.w};
                    float sh[8] = {sh0.x, sh0.y, sh0.z, sh0.w, sh1.x, sh1.y, sh1.z, sh1.w};
                    float r[8];
                    if constexpr (MODE == 1) {
                        const float4* rp = (const float4*)((const float*)Rp + (size_t)row * 128 + ch0);
                        float4 r0 = rp[0], r1 = rp[1];
                        r[0] = r0.x; r[1] = r0.y; r[2] = r0.z; r[3] = r0.w;
                        r[4] = r1.x; r[5] = r1.y; r[6] = r1.z; r[7] = r1.w;
                    } else {
                        int4 rb = *(const int4*)((const short*)Rp + (size_t)row * 128 + ch0);
                        r[0] = bflo(rb.x); r[1] = bfhi(rb.x);
                        r[2] = bflo(rb.y); r[3] = bfhi(rb.y);
                        r[4] = bflo(rb.z); r[5] = bfhi(rb.z);
                        r[6] = bflo(rb.w); r[7] = bfhi(rb.w);
                    }
                    #pragma unroll
                    for (int k = 0; k < 8; ++k)
                        v[k] = fmaxf(fmaf(v[k], sc[k], sh[k]) + r[k], 0.f);
                }
            }
            #pragma unroll
            for (int k = 0; k < 8; ++k) a[m][k] = f2bf(v[k]);
            if constexpr (MODE == 1) {
                if (row < N) *(bf16x8*)&X1[(size_t)row * 128 + ch0] = a[m];
            }
        }
        #pragma unroll
        for (int n = 0; n < NR; ++n) {
            bf16x8 b = *(const bf16x8*)&sW[n * 16 + lr][kk * 32 + lg * 8];
            acc[0][n] = __builtin_amdgcn_mfma_f32_16x16x32_bf16(a[0], b, acc[0][n], 0, 0, 0);
            acc[1][n] = __builtin_amdgcn_mfma_f32_16x16x32_bf16(a[1], b, acc[1][n], 0, 0, 0);
        }
    }

    #pragma unroll
    for (int m = 0; m < 2; ++m)
        #pragma unroll
        for (int r = 0; r < 4; ++r) {
            int row = row0 + m * 16 + lg * 4 + r;
            if (row < N) {
                #pragma unroll
                for (int n = 0; n < NR; ++n)
                    M[(size_t)row * OUTC + n * 16 + lr] = f2bf(acc[m][n][r]);
            }
        }
}

// ---------------------------------------------------------------------------
// Segment-sum aggregation over row-major bf16 M (dst sorted -> CSR).
// Wave layout: lane = g*T + t. G edge-slots x T 16B-chunks; one wave-load
// covers G edges x 256B (C=128: G=4) fully coalesced per edge; pairs of
// loads issued together for 2KB in flight. Butterfly-reduce edge-slot dim.
// Optionally accumulates BN column stats (sum,sumsq) -> LDS -> atomics.
// ---------------------------------------------------------------------------
template <int C, bool STATS>
__global__ __launch_bounds__(256) void agg_k(const short* __restrict__ M,
                                             const int* __restrict__ src,
                                             const int* __restrict__ off,
                                             const float* __restrict__ bias,
                                             float* __restrict__ H,
                                             float* __restrict__ stats, int N) {
    constexpr int T = C / 8;                 // 16B chunks per row (16 or 8)
    constexpr int G = 64 / T;                // edge slots (4 or 8)
    const int wave = threadIdx.x >> 6, lane = threadIdx.x & 63;
    const int g = lane / T, t = lane % T;
    const uint4* __restrict__ Mq = (const uint4*)M;

    float sum[8], sq[8];
    if constexpr (STATS) {
        #pragma unroll
        for (int k = 0; k < 8; ++k) { sum[k] = 0.f; sq[k] = 0.f; }
    }

    for (int node = blockIdx.x * 4 + wave; node < N; node += gridDim.x * 4) {
        const int e0 = off[node], e1 = off[node + 1];
        float acc[8];
        #pragma unroll
        for (int k = 0; k < 8; ++k) acc[k] = 0.f;

        for (int base = e0; base < e1; base += 64) {
            int cnt = e1 - base; if (cnt > 64) cnt = 64;
            int s = (base + lane < e1) ? src[base + lane] : 0;
            int ngrp = (cnt + G - 1) / G;
            for (int j = 0; j < ngrp; j += 2) {
                int i0 = j * G + g, i1 = i0 + G;
                int s0 = __shfl(s, i0), s1 = __shfl(s, i1 & 63);
                uint4 d0 = make_uint4(0u, 0u, 0u, 0u), d1 = d0;
                if (i0 < cnt) d0 = Mq[(size_t)s0 * T + t];
                if (i1 < cnt) d1 = Mq[(size_t)s1 * T + t];
                acc[0] += bflo(d0.x); acc[1] += bfhi(d0.x);
                acc[2] += bflo(d0.y); acc[3] += bfhi(d0.y);
                acc[4] += bflo(d0.z); acc[5] += bfhi(d0.z);
                acc[6] += bflo(d0.w); acc[7] += bfhi(d0.w);
                acc[0] += bflo(d1.x); acc[1] += bfhi(d1.x);
                acc[2] += bflo(d1.y); acc[3] += bfhi(d1.y);
                acc[4] += bflo(d1.z); acc[5] += bfhi(d1.z);
                acc[6] += bflo(d1.w); acc[7] += bfhi(d1.w);
            }
        }
        // reduce over edge-slot dimension (upper lane bits)
        #pragma unroll
        for (int dlt = T; dlt < 64; dlt <<= 1)
            #pragma unroll
            for (int k = 0; k < 8; ++k) acc[k] += __shfl_xor(acc[k], dlt);

        float h[8];
        #pragma unroll
        for (int k = 0; k < 8; ++k) h[k] = acc[k] + bias[t * 8 + k];
        if (g == 0) {
            *(float4*)&H[(size_t)node * C + t * 8]     = make_float4(h[0], h[1], h[2], h[3]);
            *(float4*)&H[(size_t)node * C + t * 8 + 4] = make_float4(h[4], h[5], h[6], h[7]);
            if constexpr (STATS) {
                #pragma unroll
                for (int k = 0; k < 8; ++k) {
                    sum[k] += h[k]; sq[k] = fmaf(h[k], h[k], sq[k]);
                }
            }
        }
    }

    if constexpr (STATS) {
        __shared__ float sL[4 * 256];
        if (g == 0) {
            #pragma unroll
            for (int k = 0; k < 8; ++k) {
                sL[wave * 256 + t * 8 + k]       = sum[k];
                sL[wave * 256 + 128 + t * 8 + k] = sq[k];
            }
        }
        __syncthreads();
        int tid = threadIdx.x;
        float v = sL[tid] + sL[256 + tid] + sL[512 + tid] + sL[768 + tid];
        atomicAdd(&stats[tid], v);
    }
}

// stats -> per-channel scale/shift:  out = h*sc + sh
__global__ void bnfin_k(const float* __restrict__ stats, const float* __restrict__ gamma,
                        const float* __restrict__ beta, float* __restrict__ ss, float invN) {
    int c = threadIdx.x;   // 128 threads
    float mu  = stats[c] * invN;
    float var = fmaf(-mu, mu, stats[128 + c] * invN);
    float sc  = gamma[c] * rsqrtf(var + BN_EPS);
    ss[c]       = sc;
    ss[128 + c] = fmaf(-mu, sc, beta[c]);
}

// ---------------------------------------------------------------------------
extern "C" void kernel_launch(void* const* d_in, const int* in_sizes, int n_in,
                              void* d_out, int out_size, void* d_ws, size_t ws_size,
                              hipStream_t stream) {
    const float* x   = (const float*)d_in[0];
    const int*   src = (const int*)d_in[1];
    const int*   dst = (const int*)d_in[2];
    const float* W0  = (const float*)d_in[3];
    const float* b0  = (const float*)d_in[4];
    const float* W1  = (const float*)d_in[5];
    const float* b1  = (const float*)d_in[6];
    const float* W2  = (const float*)d_in[7];
    const float* b2  = (const float*)d_in[8];
    const float* g0  = (const float*)d_in[9];
    const float* be0 = (const float*)d_in[10];
    const float* g1  = (const float*)d_in[11];
    const float* be1 = (const float*)d_in[12];
    float* out = (float*)d_out;

    const int N = in_sizes[0] / 128;
    const int E = in_sizes[1];

    // workspace: bf16 M (N x 128) + fp32 H (N x 128) + bf16 X1 (N x 128) + misc
    char*  ws   = (char*)d_ws;
    size_t bufB = (size_t)N * 128 * sizeof(float);
    short* Mb = (short*)(ws);                 // N x 128 bf16 row-major
    float* H  = (float*)(ws + bufB);          // pre-BN conv output, fp32
    short* X1 = (short*)(ws + 2 * bufB);      // post-layer-1 activations, bf16
    size_t p  = 2 * bufB + bufB / 2;
    p = (p + 255) & ~(size_t)255;
    int*   off = (int*)(ws + p);
    p += ((size_t)(N + 1) * sizeof(int) + 255) & ~(size_t)255;
    float* stats0 = (float*)(ws + p); p += 1024;
    float* stats1 = (float*)(ws + p); p += 1024;
    float* ss0    = (float*)(ws + p); p += 1024;
    float* ss1    = (float*)(ws + p); p += 1024;
    short* Wt0    = (short*)(ws + p); p += 128 * 128 * 2;
    short* Wt1    = (short*)(ws + p); p += 128 * 128 * 2;
    short* Wt2    = (short*)(ws + p); p += 128 * 64 * 2;

    const dim3 blk(256);
    const int gGemm = (N + 127) / 128;
    const int gAgg  = 1024;
    const float invN = 1.f / (float)N;

    zero_k<<<2, blk, 0, stream>>>(stats0, 512);   // stats0+stats1 contiguous
    wtrans_k<<<64, blk, 0, stream>>>(W0, Wt0, 128, 128);
    wtrans_k<<<64, blk, 0, stream>>>(W1, Wt1, 128, 128);
    wtrans_k<<<32, blk, 0, stream>>>(W2, Wt2, 128, 64);
    build_off_k<<<(E + 256) / 256, blk, 0, stream>>>(dst, off, E, N);

    // ---- layer 0: M0 = bf16(x) @ W0 ; H0 = agg(M0)+b0 (+stats) ----
    mgemm_k<128, 0><<<gGemm, blk, 0, stream>>>(x, Wt0, Mb, nullptr, nullptr, nullptr, N);
    agg_k<128, true><<<gAgg, blk, 0, stream>>>(Mb, src, off, b0, H, stats0, N);
    bnfin_k<<<1, 128, 0, stream>>>(stats0, g0, be0, ss0, invN);

    // ---- layer 1: x1 = relu(BN(H0)+x) fused into GEMM; M1 = x1 @ W1 ----
    mgemm_k<128, 1><<<gGemm, blk, 0, stream>>>(H, Wt1, Mb, ss0, x, X1, N);
    agg_k<128, true><<<gAgg, blk, 0, stream>>>(Mb, src, off, b1, H, stats1, N);
    bnfin_k<<<1, 128, 0, stream>>>(stats1, g1, be1, ss1, invN);

    // ---- layer 2: x2 = relu(BN(H1)+x1) fused; M2 = x2 @ W2 ; out = agg+b2 ----
    mgemm_k<64, 2><<<gGemm, blk, 0, stream>>>(H, Wt2, Mb, ss1, X1, nullptr, N);
    agg_k<64, false><<<gAgg, blk, 0, stream>>>(Mb, src, off, b2, out, stats0, N);
}